// Round 1
// baseline (2449.882 us; speedup 1.0000x reference)
//
#include <hip/hip_runtime.h>
#include <math.h>

#define B 8
#define S 2048
#define D_MODEL 512
#define NK 256      // n_kernels (conv output channels / attention feature dim)
#define KSZ 9
#define NC 4096     // n_classes
#define PADW 4
#define TS 16       // conv s-tile
#define CT 64       // attn classes per block
#define STL 32      // attn s-tile

// ---------------- weight transpose: conv_w [k][d][t] -> wt [d][t][k] -------
__global__ __launch_bounds__(256) void transpose_convw(
    const float* __restrict__ w, float* __restrict__ wt)
{
    int idx = blockIdx.x * 256 + threadIdx.x;          // over D*KSZ*NK = 1179648
    if (idx >= D_MODEL * KSZ * NK) return;
    int k = idx % NK;
    int t = (idx / NK) % KSZ;
    int d = idx / (NK * KSZ);
    wt[idx] = w[((size_t)k * D_MODEL + d) * KSZ + t];
}

// ---------------- embed-gather + conv1d + bias + tanh -> x_feat [b][s][k] --
__global__ __launch_bounds__(256) void conv_kernel(
    const int* __restrict__ text, const float* __restrict__ emb,
    const float* __restrict__ wt, const float* __restrict__ bias,
    float* __restrict__ xf)
{
    __shared__ float xs[(TS + KSZ - 1) * D_MODEL];     // 24*512 fp32 = 48 KB
    const int b  = blockIdx.y;
    const int s0 = blockIdx.x * TS;
    const int tid = threadIdx.x;

    // Stage window rows s0-4 .. s0+19 (gather embed rows straight into LDS).
    const int nf4 = (TS + KSZ - 1) * D_MODEL / 4;      // 3072 float4
    for (int i = tid; i < nf4; i += 256) {
        int row  = i / (D_MODEL / 4);
        int col4 = i % (D_MODEL / 4);
        int gs = s0 + row - PADW;
        float4 v = make_float4(0.f, 0.f, 0.f, 0.f);
        if (gs >= 0 && gs < S) {
            int tok = text[(size_t)b * S + gs];
            v = ((const float4*)(emb + (size_t)tok * D_MODEL))[col4];
        }
        ((float4*)xs)[i] = v;
    }
    __syncthreads();

    const int k = tid;                                  // one output channel/thread
    float acc[TS];
    #pragma unroll
    for (int s = 0; s < TS; s++) acc[s] = 0.f;

    for (int d = 0; d < D_MODEL; d++) {
        float w[KSZ];
        #pragma unroll
        for (int t = 0; t < KSZ; t++)
            w[t] = wt[((size_t)d * KSZ + t) * NK + k];  // lane-contiguous (coalesced)
        float xv[TS + KSZ - 1];
        #pragma unroll
        for (int r = 0; r < TS + KSZ - 1; r++)
            xv[r] = xs[r * D_MODEL + d];                // wave-uniform (broadcast)
        #pragma unroll
        for (int s = 0; s < TS; s++) {
            float a = acc[s];
            #pragma unroll
            for (int t = 0; t < KSZ; t++)
                a = fmaf(xv[s + t], w[t], a);
            acc[s] = a;
        }
    }
    const float bk = bias[k];
    #pragma unroll
    for (int s = 0; s < TS; s++)
        xf[(((size_t)b * S) + s0 + s) * NK + k] = tanhf(acc[s] + bk);
}

// -------- fused scores/g GEMM + online softmax + readout -> y [b][c] -------
__global__ __launch_bounds__(256) void attn_kernel(
    const float* __restrict__ xf, const float* __restrict__ Uw,
    const float* __restrict__ Fw, const float* __restrict__ fb,
    float* __restrict__ out)
{
    __shared__ float xs[STL * NK];                      // 32*256 fp32 = 32 KB
    __shared__ float red_m[4][CT], red_l[4][CT], red_g[4][CT];
    const int b   = blockIdx.y;
    const int c0  = blockIdx.x * CT;
    const int tid = threadIdx.x;
    const int cl  = tid & 63;                           // class-local (lane)
    const int sg  = tid >> 6;                           // s-group 0..3
    const int c   = c0 + cl;

    const float4* U4 = (const float4*)(Uw + (size_t)c * NK);
    const float4* F4 = (const float4*)(Fw + (size_t)c * NK);

    float m = -1e30f, l = 0.f, G = 0.f;

    for (int st = 0; st < S; st += STL) {
        const float4* src = (const float4*)(xf + ((size_t)b * S + st) * NK);
        #pragma unroll
        for (int i = 0; i < (STL * NK / 4) / 256; i++)  // 8 float4 / thread
            ((float4*)xs)[tid + i * 256] = src[tid + i * 256];
        __syncthreads();

        float as[8], ag[8];
        #pragma unroll
        for (int j = 0; j < 8; j++) { as[j] = 0.f; ag[j] = 0.f; }

        for (int kk = 0; kk < NK / 4; kk++) {
            float4 u = U4[kk];
            float4 f = F4[kk];
            #pragma unroll
            for (int j = 0; j < 8; j++) {
                float4 x = ((const float4*)(xs + (sg * 8 + j) * NK))[kk]; // broadcast b128
                as[j] = fmaf(u.x, x.x, as[j]);
                as[j] = fmaf(u.y, x.y, as[j]);
                as[j] = fmaf(u.z, x.z, as[j]);
                as[j] = fmaf(u.w, x.w, as[j]);
                ag[j] = fmaf(f.x, x.x, ag[j]);
                ag[j] = fmaf(f.y, x.y, ag[j]);
                ag[j] = fmaf(f.z, x.z, ag[j]);
                ag[j] = fmaf(f.w, x.w, ag[j]);
            }
        }
        // online softmax update over this tile's 8 scores
        #pragma unroll
        for (int j = 0; j < 8; j++) {
            float sc = as[j];
            float mn = fmaxf(m, sc);
            float scale = __expf(m - mn);
            float e     = __expf(sc - mn);
            l = l * scale + e;
            G = G * scale + e * ag[j];
            m = mn;
        }
        __syncthreads();
    }

    red_m[sg][cl] = m; red_l[sg][cl] = l; red_g[sg][cl] = G;
    __syncthreads();
    if (sg == 0) {
        float mm = red_m[0][cl];
        #pragma unroll
        for (int i = 1; i < 4; i++) mm = fmaxf(mm, red_m[i][cl]);
        float ll = 0.f, gg = 0.f;
        #pragma unroll
        for (int i = 0; i < 4; i++) {
            float sc = __expf(red_m[i][cl] - mm);
            ll += red_l[i][cl] * sc;
            gg += red_g[i][cl] * sc;
        }
        out[(size_t)b * NC + c] = gg / ll + fb[c];
    }
}

extern "C" void kernel_launch(void* const* d_in, const int* in_sizes, int n_in,
                              void* d_out, int out_size, void* d_ws, size_t ws_size,
                              hipStream_t stream) {
    const int*   text   = (const int*)  d_in[0];
    const float* emb    = (const float*)d_in[1];
    const float* conv_w = (const float*)d_in[2];
    const float* conv_b = (const float*)d_in[3];
    const float* U_w    = (const float*)d_in[4];
    const float* F_w    = (const float*)d_in[5];
    const float* f_b    = (const float*)d_in[6];
    float* out = (float*)d_out;

    float* ws = (float*)d_ws;
    float* xf = ws;                                   // B*S*NK      = 4,194,304 f
    float* wt = ws + (size_t)B * S * NK;              // D*KSZ*NK    = 1,179,648 f

    transpose_convw<<<dim3((D_MODEL * KSZ * NK + 255) / 256), 256, 0, stream>>>(conv_w, wt);
    conv_kernel<<<dim3(S / TS, B), 256, 0, stream>>>(text, emb, wt, conv_b, xf);
    attn_kernel<<<dim3(NC / CT, B), 256, 0, stream>>>(xf, U_w, F_w, f_b, out);
}

// Round 2
// 850.471 us; speedup vs baseline: 2.8806x; 2.8806x over previous
//
#include <hip/hip_runtime.h>
#include <math.h>

#define B 8
#define S 2048
#define D_MODEL 512
#define NK 256      // n_kernels (conv out channels / attention feature dim)
#define KSZ 9
#define NC 4096     // n_classes
#define PADW 4
#define TS 16       // conv s-tile
#define SSPLIT 2    // attention s-dimension split (partials combined at end)

typedef __attribute__((ext_vector_type(8))) short bf16x8;
typedef __attribute__((ext_vector_type(4))) float f32x4;

static __device__ __forceinline__ unsigned short f2bf(float f) {
    unsigned int u = __float_as_uint(f);
    unsigned int r = (u + 0x7fffu + ((u >> 16) & 1u)) >> 16;
    return (unsigned short)r;
}

// ---------------- weight transpose: conv_w [k][d][t] -> wt [d][t][k] -------
__global__ __launch_bounds__(256) void transpose_convw(
    const float* __restrict__ w, float* __restrict__ wt)
{
    int idx = blockIdx.x * 256 + threadIdx.x;          // over D*KSZ*NK
    if (idx >= D_MODEL * KSZ * NK) return;
    int k = idx % NK;
    int t = (idx / NK) % KSZ;
    int d = idx / (NK * KSZ);
    wt[idx] = w[((size_t)k * D_MODEL + d) * KSZ + t];
}

// ---------------- fp32 -> bf16 elementwise convert -------------------------
__global__ __launch_bounds__(256) void to_bf16(
    const float* __restrict__ in, unsigned short* __restrict__ out, int n)
{
    int idx = blockIdx.x * 256 + threadIdx.x;
    if (idx < n) out[idx] = f2bf(in[idx]);
}

// ---------------- embed-gather + conv1d + bias + tanh -> xf bf16 [b][s][k] -
__global__ __launch_bounds__(256) void conv_kernel(
    const int* __restrict__ text, const float* __restrict__ emb,
    const float* __restrict__ wt, const float* __restrict__ bias,
    unsigned short* __restrict__ xf)
{
    __shared__ float xs[(TS + KSZ - 1) * D_MODEL];     // 24*512 fp32 = 48 KB
    const int b  = blockIdx.y;
    const int s0 = blockIdx.x * TS;
    const int tid = threadIdx.x;

    const int nf4 = (TS + KSZ - 1) * D_MODEL / 4;      // 3072 float4
    for (int i = tid; i < nf4; i += 256) {
        int row  = i / (D_MODEL / 4);
        int col4 = i % (D_MODEL / 4);
        int gs = s0 + row - PADW;
        float4 v = make_float4(0.f, 0.f, 0.f, 0.f);
        if (gs >= 0 && gs < S) {
            int tok = text[(size_t)b * S + gs];
            v = ((const float4*)(emb + (size_t)tok * D_MODEL))[col4];
        }
        ((float4*)xs)[i] = v;
    }
    __syncthreads();

    const int k = tid;                                  // one output channel/thread
    float acc[TS];
    #pragma unroll
    for (int s = 0; s < TS; s++) acc[s] = 0.f;

    for (int d = 0; d < D_MODEL; d++) {
        float w[KSZ];
        #pragma unroll
        for (int t = 0; t < KSZ; t++)
            w[t] = wt[((size_t)d * KSZ + t) * NK + k];  // lane-contiguous
        float xv[TS + KSZ - 1];
        #pragma unroll
        for (int r = 0; r < TS + KSZ - 1; r++)
            xv[r] = xs[r * D_MODEL + d];                // wave-uniform broadcast
        #pragma unroll
        for (int s = 0; s < TS; s++) {
            float a = acc[s];
            #pragma unroll
            for (int t = 0; t < KSZ; t++)
                a = fmaf(xv[s + t], w[t], a);
            acc[s] = a;
        }
    }
    const float bk = bias[k];
    #pragma unroll
    for (int s = 0; s < TS; s++)
        xf[(((size_t)b * S) + s0 + s) * NK + k] = f2bf(tanhf(acc[s] + bk));
}

// -------- MFMA flash attention: per wave 16 classes, online softmax --------
// scores[s,c] = x[s,:]·U[c,:]  via mfma_f32_16x16x32_bf16 (A = x rows,
// B = U rows: both fragments are 8 contiguous bf16 — no transpose needed).
// C/D layout: col = class = lane&15, row = s = quad*4 + reg.
__global__ __launch_bounds__(256) void attn_mfma(
    const unsigned short* __restrict__ xf, const unsigned short* __restrict__ Ub,
    const unsigned short* __restrict__ Fb, float* __restrict__ pm,
    float* __restrict__ pl, float* __restrict__ pg)
{
    const int b    = blockIdx.z;
    const int sp   = blockIdx.y;
    const int wv   = threadIdx.x >> 6;
    const int lane = threadIdx.x & 63;
    const int cl   = lane & 15;
    const int quad = lane >> 4;
    const int c0   = blockIdx.x * 64 + wv * 16;

    // Resident B-fragments for U and F (16 classes x 256 k): 64 VGPRs.
    bf16x8 uf[8], ff[8];
    const unsigned short* up = Ub + (size_t)(c0 + cl) * NK + quad * 8;
    const unsigned short* fp = Fb + (size_t)(c0 + cl) * NK + quad * 8;
    #pragma unroll
    for (int kk = 0; kk < 8; kk++) {
        uf[kk] = *(const bf16x8*)(up + kk * 32);
        ff[kk] = *(const bf16x8*)(fp + kk * 32);
    }

    const unsigned short* xb = xf + (size_t)b * S * NK;
    const int sbeg = sp * (S / SSPLIT);
    float m = -1e30f, l = 0.f, G = 0.f;

    for (int s0 = sbeg; s0 < sbeg + S / SSPLIT; s0 += 16) {
        const unsigned short* xp = xb + (size_t)(s0 + cl) * NK + quad * 8;
        bf16x8 af[8];
        #pragma unroll
        for (int kk = 0; kk < 8; kk++)
            af[kk] = *(const bf16x8*)(xp + kk * 32);

        f32x4 sacc = {0.f, 0.f, 0.f, 0.f};
        f32x4 gacc = {0.f, 0.f, 0.f, 0.f};
        #pragma unroll
        for (int kk = 0; kk < 8; kk++) {
            sacc = __builtin_amdgcn_mfma_f32_16x16x32_bf16(af[kk], uf[kk], sacc, 0, 0, 0);
            gacc = __builtin_amdgcn_mfma_f32_16x16x32_bf16(af[kk], ff[kk], gacc, 0, 0, 0);
        }

        // online softmax over this tile's 16 s-rows (4 in-lane + 2 shuffles)
        float tm = fmaxf(fmaxf(sacc[0], sacc[1]), fmaxf(sacc[2], sacc[3]));
        tm = fmaxf(tm, __shfl_xor(tm, 16));
        tm = fmaxf(tm, __shfl_xor(tm, 32));
        float mn = fmaxf(m, tm);
        float sc = __expf(m - mn);
        l *= sc; G *= sc; m = mn;
        #pragma unroll
        for (int r = 0; r < 4; r++) {
            float e = __expf(sacc[r] - m);
            l += e;
            G += e * gacc[r];
        }
    }

    // reduce partial l/G across the 4 quads (m already quad-uniform)
    l += __shfl_xor(l, 16); l += __shfl_xor(l, 32);
    G += __shfl_xor(G, 16); G += __shfl_xor(G, 32);
    if (lane < 16) {
        size_t idx = ((size_t)b * SSPLIT + sp) * NC + c0 + lane;
        pm[idx] = m; pl[idx] = l; pg[idx] = G;
    }
}

// -------- combine S-split partials + bias -> y [b][c] ----------------------
__global__ __launch_bounds__(256) void combine_kernel(
    const float* __restrict__ pm, const float* __restrict__ pl,
    const float* __restrict__ pg, const float* __restrict__ fb,
    float* __restrict__ out)
{
    int idx = blockIdx.x * 256 + threadIdx.x;          // over B*NC
    if (idx >= B * NC) return;
    int b = idx / NC, c = idx % NC;
    float mm = -1e30f;
    #pragma unroll
    for (int sp = 0; sp < SSPLIT; sp++)
        mm = fmaxf(mm, pm[((size_t)b * SSPLIT + sp) * NC + c]);
    float l = 0.f, g = 0.f;
    #pragma unroll
    for (int sp = 0; sp < SSPLIT; sp++) {
        size_t i = ((size_t)b * SSPLIT + sp) * NC + c;
        float e = __expf(pm[i] - mm);
        l += pl[i] * e;
        g += pg[i] * e;
    }
    out[idx] = g / l + fb[c];
}

extern "C" void kernel_launch(void* const* d_in, const int* in_sizes, int n_in,
                              void* d_out, int out_size, void* d_ws, size_t ws_size,
                              hipStream_t stream) {
    const int*   text   = (const int*)  d_in[0];
    const float* emb    = (const float*)d_in[1];
    const float* conv_w = (const float*)d_in[2];
    const float* conv_b = (const float*)d_in[3];
    const float* U_w    = (const float*)d_in[4];
    const float* F_w    = (const float*)d_in[5];
    const float* f_b    = (const float*)d_in[6];
    float* out = (float*)d_out;

    char* ws = (char*)d_ws;
    unsigned short* xf = (unsigned short*)ws;                 // B*S*NK bf16 = 8 MB
    ws += (size_t)B * S * NK * 2;
    float* wt = (float*)ws;                                   // D*KSZ*NK f32 = 4.7 MB
    ws += (size_t)D_MODEL * KSZ * NK * 4;
    unsigned short* Ub = (unsigned short*)ws;                 // NC*NK bf16 = 2 MB
    ws += (size_t)NC * NK * 2;
    unsigned short* Fb = (unsigned short*)ws;                 // NC*NK bf16 = 2 MB
    ws += (size_t)NC * NK * 2;
    float* pm = (float*)ws; ws += (size_t)SSPLIT * B * NC * 4;
    float* pl = (float*)ws; ws += (size_t)SSPLIT * B * NC * 4;
    float* pg = (float*)ws; ws += (size_t)SSPLIT * B * NC * 4;

    transpose_convw<<<dim3((D_MODEL * KSZ * NK + 255) / 256), 256, 0, stream>>>(conv_w, wt);
    to_bf16<<<dim3((NC * NK + 255) / 256), 256, 0, stream>>>(U_w, Ub, NC * NK);
    to_bf16<<<dim3((NC * NK + 255) / 256), 256, 0, stream>>>(F_w, Fb, NC * NK);
    conv_kernel<<<dim3(S / TS, B), 256, 0, stream>>>(text, emb, wt, conv_b, xf);
    attn_mfma<<<dim3(NC / 64, SSPLIT, B), 256, 0, stream>>>(xf, Ub, Fb, pm, pl, pg);
    combine_kernel<<<dim3((B * NC + 255) / 256), 256, 0, stream>>>(pm, pl, pg, f_b, out);
}

// Round 3
// 432.936 us; speedup vs baseline: 5.6588x; 1.9644x over previous
//
#include <hip/hip_runtime.h>
#include <math.h>

#define B 8
#define S 2048
#define D_MODEL 512
#define NK 256      // n_kernels (conv out channels / attention feature dim)
#define KSZ 9
#define NC 4096     // n_classes
#define PADW 4
#define SSPLIT 2    // attention s-dimension split
#define CM 64       // conv s-rows per block
#define CW (CM + 8) // staged window rows
#define LRS 520     // LDS row stride (bf16) — 1040 B = 4-bank shift per row

typedef __attribute__((ext_vector_type(8))) short bf16x8;
typedef __attribute__((ext_vector_type(4))) float f32x4;

static __device__ __forceinline__ unsigned short f2bf(float f) {
    unsigned int u = __float_as_uint(f);
    unsigned int r = (u + 0x7fffu + ((u >> 16) & 1u)) >> 16;
    return (unsigned short)r;
}

// ---- conv_w [k][d][t] fp32 -> wtb [t][k][d] bf16 --------------------------
__global__ __launch_bounds__(256) void prep_convw(
    const float* __restrict__ w, unsigned short* __restrict__ wtb)
{
    int idx = blockIdx.x * 256 + threadIdx.x;          // over KSZ*NK*D
    if (idx >= KSZ * NK * D_MODEL) return;
    int d = idx % D_MODEL;
    int k = (idx / D_MODEL) % NK;
    int t = idx / (D_MODEL * NK);
    wtb[idx] = f2bf(w[((size_t)k * D_MODEL + d) * KSZ + t]);
}

// ---- fp32 -> bf16 elementwise ---------------------------------------------
__global__ __launch_bounds__(256) void to_bf16(
    const float* __restrict__ in, unsigned short* __restrict__ out, int n)
{
    int idx = blockIdx.x * 256 + threadIdx.x;
    if (idx < n) out[idx] = f2bf(in[idx]);
}

// ---- embed-gather + MFMA conv1d + bias + tanh -> xf bf16 [b][s][k] --------
// Per tap t: out[s][k] += sum_d win[s+t][d] * w[k][d][t]  (16x16x32 bf16 MFMA)
// A-frag: 8 contiguous bf16 from LDS window row (shifted by t).
// B-frag: 8 contiguous bf16 from wtb[t][k][d].
__global__ __launch_bounds__(512) void conv_mfma(
    const int* __restrict__ text, const float* __restrict__ emb,
    const unsigned short* __restrict__ wtb, const float* __restrict__ bias,
    unsigned short* __restrict__ xf)
{
    __shared__ unsigned short xs[CW * LRS];            // 74,880 B
    const int b  = blockIdx.x >> 5;
    const int s0 = (blockIdx.x & 31) * CM;
    const int tid = threadIdx.x;

    // stage window rows s0-4 .. s0+67 (embed gather, fp32 -> bf16)
    for (int i = tid; i < CW * (D_MODEL / 4); i += 512) {
        int row = i >> 7;                              // / (D_MODEL/4)
        int c4  = i & 127;
        int gs = s0 + row - PADW;
        float4 v = make_float4(0.f, 0.f, 0.f, 0.f);
        if (gs >= 0 && gs < S) {
            int tok = text[b * S + gs];
            v = ((const float4*)(emb + (size_t)tok * D_MODEL))[c4];
        }
        ushort4 o;
        o.x = f2bf(v.x); o.y = f2bf(v.y); o.z = f2bf(v.z); o.w = f2bf(v.w);
        *(ushort4*)(xs + row * LRS + c4 * 4) = o;
    }
    __syncthreads();

    const int wv   = tid >> 6;                         // 0..7
    const int lane = tid & 63;
    const int cl   = lane & 15;
    const int quad = lane >> 4;
    const int n0   = wv * 32;                          // wave's k-channel base

    f32x4 acc[4][2] = {};                              // [Msub][Nsub]

    for (int t = 0; t < KSZ; t++) {
        const unsigned short* wp =
            wtb + ((size_t)t * NK + n0 + cl) * D_MODEL + quad * 8;
        const unsigned short* ap = xs + (cl + t) * LRS + quad * 8;
        #pragma unroll 4
        for (int dc = 0; dc < D_MODEL / 32; dc++) {
            bf16x8 bfr0 = *(const bf16x8*)(wp + dc * 32);
            bf16x8 bfr1 = *(const bf16x8*)(wp + 16 * D_MODEL + dc * 32);
            bf16x8 afr[4];
            #pragma unroll
            for (int ms = 0; ms < 4; ms++)
                afr[ms] = *(const bf16x8*)(ap + ms * 16 * LRS + dc * 32);
            #pragma unroll
            for (int ms = 0; ms < 4; ms++) {
                acc[ms][0] = __builtin_amdgcn_mfma_f32_16x16x32_bf16(afr[ms], bfr0, acc[ms][0], 0, 0, 0);
                acc[ms][1] = __builtin_amdgcn_mfma_f32_16x16x32_bf16(afr[ms], bfr1, acc[ms][1], 0, 0, 0);
            }
        }
    }

    // epilogue: bias + tanh -> bf16 store. C-layout: s=Msub*16+quad*4+r, k=Nsub*16+cl
    #pragma unroll
    for (int ns = 0; ns < 2; ns++) {
        const int k = n0 + ns * 16 + cl;
        const float bk = bias[k];
        #pragma unroll
        for (int ms = 0; ms < 4; ms++) {
            #pragma unroll
            for (int r = 0; r < 4; r++) {
                int s = s0 + ms * 16 + quad * 4 + r;
                float v = acc[ms][ns][r] + bk;
                float e = __expf(2.f * v);
                float th = 1.f - 2.f / (e + 1.f);      // tanh(v)
                xf[((size_t)b * S + s) * NK + k] = f2bf(th);
            }
        }
    }
}

// -------- MFMA flash attention: per wave 16 classes, online softmax --------
__global__ __launch_bounds__(256) void attn_mfma(
    const unsigned short* __restrict__ xf, const unsigned short* __restrict__ Ub,
    const unsigned short* __restrict__ Fb, float* __restrict__ pm,
    float* __restrict__ pl, float* __restrict__ pg)
{
    const int b    = blockIdx.z;
    const int sp   = blockIdx.y;
    const int wv   = threadIdx.x >> 6;
    const int lane = threadIdx.x & 63;
    const int cl   = lane & 15;
    const int quad = lane >> 4;
    const int c0   = blockIdx.x * 64 + wv * 16;

    bf16x8 uf[8], ff[8];
    const unsigned short* up = Ub + (size_t)(c0 + cl) * NK + quad * 8;
    const unsigned short* fp = Fb + (size_t)(c0 + cl) * NK + quad * 8;
    #pragma unroll
    for (int kk = 0; kk < 8; kk++) {
        uf[kk] = *(const bf16x8*)(up + kk * 32);
        ff[kk] = *(const bf16x8*)(fp + kk * 32);
    }

    const unsigned short* xb = xf + (size_t)b * S * NK;
    const int sbeg = sp * (S / SSPLIT);
    float m = -1e30f, l = 0.f, G = 0.f;

    for (int s0 = sbeg; s0 < sbeg + S / SSPLIT; s0 += 16) {
        const unsigned short* xp = xb + (size_t)(s0 + cl) * NK + quad * 8;
        bf16x8 af[8];
        #pragma unroll
        for (int kk = 0; kk < 8; kk++)
            af[kk] = *(const bf16x8*)(xp + kk * 32);

        f32x4 sacc = {0.f, 0.f, 0.f, 0.f};
        f32x4 gacc = {0.f, 0.f, 0.f, 0.f};
        #pragma unroll
        for (int kk = 0; kk < 8; kk++) {
            sacc = __builtin_amdgcn_mfma_f32_16x16x32_bf16(af[kk], uf[kk], sacc, 0, 0, 0);
            gacc = __builtin_amdgcn_mfma_f32_16x16x32_bf16(af[kk], ff[kk], gacc, 0, 0, 0);
        }

        float tm = fmaxf(fmaxf(sacc[0], sacc[1]), fmaxf(sacc[2], sacc[3]));
        tm = fmaxf(tm, __shfl_xor(tm, 16));
        tm = fmaxf(tm, __shfl_xor(tm, 32));
        float mn = fmaxf(m, tm);
        float sc = __expf(m - mn);
        l *= sc; G *= sc; m = mn;
        #pragma unroll
        for (int r = 0; r < 4; r++) {
            float e = __expf(sacc[r] - m);
            l += e;
            G += e * gacc[r];
        }
    }

    l += __shfl_xor(l, 16); l += __shfl_xor(l, 32);
    G += __shfl_xor(G, 16); G += __shfl_xor(G, 32);
    if (lane < 16) {
        size_t idx = ((size_t)b * SSPLIT + sp) * NC + c0 + lane;
        pm[idx] = m; pl[idx] = l; pg[idx] = G;
    }
}

// -------- combine S-split partials + bias -> y [b][c] ----------------------
__global__ __launch_bounds__(256) void combine_kernel(
    const float* __restrict__ pm, const float* __restrict__ pl,
    const float* __restrict__ pg, const float* __restrict__ fb,
    float* __restrict__ out)
{
    int idx = blockIdx.x * 256 + threadIdx.x;          // over B*NC
    if (idx >= B * NC) return;
    int b = idx / NC, c = idx % NC;
    float mm = -1e30f;
    #pragma unroll
    for (int sp = 0; sp < SSPLIT; sp++)
        mm = fmaxf(mm, pm[((size_t)b * SSPLIT + sp) * NC + c]);
    float l = 0.f, g = 0.f;
    #pragma unroll
    for (int sp = 0; sp < SSPLIT; sp++) {
        size_t i = ((size_t)b * SSPLIT + sp) * NC + c;
        float e = __expf(pm[i] - mm);
        l += pl[i] * e;
        g += pg[i] * e;
    }
    out[idx] = g / l + fb[c];
}

extern "C" void kernel_launch(void* const* d_in, const int* in_sizes, int n_in,
                              void* d_out, int out_size, void* d_ws, size_t ws_size,
                              hipStream_t stream) {
    const int*   text   = (const int*)  d_in[0];
    const float* emb    = (const float*)d_in[1];
    const float* conv_w = (const float*)d_in[2];
    const float* conv_b = (const float*)d_in[3];
    const float* U_w    = (const float*)d_in[4];
    const float* F_w    = (const float*)d_in[5];
    const float* f_b    = (const float*)d_in[6];
    float* out = (float*)d_out;

    char* ws = (char*)d_ws;
    unsigned short* xf  = (unsigned short*)ws; ws += (size_t)B * S * NK * 2;
    unsigned short* wtb = (unsigned short*)ws; ws += (size_t)KSZ * NK * D_MODEL * 2;
    unsigned short* Ub  = (unsigned short*)ws; ws += (size_t)NC * NK * 2;
    unsigned short* Fb  = (unsigned short*)ws; ws += (size_t)NC * NK * 2;
    float* pm = (float*)ws; ws += (size_t)SSPLIT * B * NC * 4;
    float* pl = (float*)ws; ws += (size_t)SSPLIT * B * NC * 4;
    float* pg = (float*)ws; ws += (size_t)SSPLIT * B * NC * 4;

    prep_convw<<<dim3((KSZ * NK * D_MODEL + 255) / 256), 256, 0, stream>>>(conv_w, wtb);
    to_bf16<<<dim3((NC * NK + 255) / 256), 256, 0, stream>>>(U_w, Ub, NC * NK);
    to_bf16<<<dim3((NC * NK + 255) / 256), 256, 0, stream>>>(F_w, Fb, NC * NK);
    conv_mfma<<<dim3(B * S / CM), 512, 0, stream>>>(text, emb, wtb, conv_b, xf);
    attn_mfma<<<dim3(NC / 64, SSPLIT, B), 256, 0, stream>>>(xf, Ub, Fb, pm, pl, pg);
    combine_kernel<<<dim3((B * NC + 255) / 256), 256, 0, stream>>>(pm, pl, pg, f_b, out);
}

// Round 4
// 313.741 us; speedup vs baseline: 7.8086x; 1.3799x over previous
//
#include <hip/hip_runtime.h>
#include <math.h>

#define B 8
#define S 2048
#define D_MODEL 512
#define NK 256      // n_kernels (conv out channels / attention feature dim)
#define KSZ 9
#define NC 4096     // n_classes
#define PADW 4
#define SSPLIT 4    // attention s-dimension split
#define CM 32       // conv s-rows per block
#define CW (CM + 8) // staged window rows (40)
#define LRS 520     // conv LDS row stride (bf16)
#define NTILES ((S / SSPLIT) / 32)   // 16 tiles of 32 rows per attn block

typedef __attribute__((ext_vector_type(8))) short bf16x8;
typedef __attribute__((ext_vector_type(4))) float f32x4;

static __device__ __forceinline__ unsigned short f2bf(float f) {
    unsigned int u = __float_as_uint(f);
    unsigned int r = (u + 0x7fffu + ((u >> 16) & 1u)) >> 16;
    return (unsigned short)r;
}

#define GLOAD_LDS16(g, l) __builtin_amdgcn_global_load_lds( \
    (const __attribute__((address_space(1))) void*)(g),     \
    (__attribute__((address_space(3))) void*)(l), 16, 0, 0)

// ---- fused prep: conv_w [k][d][t] -> wtb [t][k][d] bf16; U/F fp32 -> bf16 -
#define PREP_W (KSZ * NK * D_MODEL)
#define PREP_UF (NC * NK)
__global__ __launch_bounds__(256) void prep_all(
    const float* __restrict__ w, unsigned short* __restrict__ wtb,
    const float* __restrict__ U, unsigned short* __restrict__ Ub,
    const float* __restrict__ F, unsigned short* __restrict__ Fb)
{
    int idx = blockIdx.x * 256 + threadIdx.x;
    if (idx < PREP_W) {
        int d = idx % D_MODEL;
        int k = (idx / D_MODEL) % NK;
        int t = idx / (D_MODEL * NK);
        wtb[idx] = f2bf(w[((size_t)k * D_MODEL + d) * KSZ + t]);
        return;
    }
    idx -= PREP_W;
    if (idx < PREP_UF) { Ub[idx] = f2bf(U[idx]); return; }
    idx -= PREP_UF;
    if (idx < PREP_UF) { Fb[idx] = f2bf(F[idx]); }
}

// ---- embed-gather + MFMA conv1d + bias + tanh -> xf bf16 [b][s][k] --------
__global__ __launch_bounds__(512) void conv_mfma(
    const int* __restrict__ text, const float* __restrict__ emb,
    const unsigned short* __restrict__ wtb, const float* __restrict__ bias,
    unsigned short* __restrict__ xf)
{
    __shared__ unsigned short xs[CW * LRS];            // 40*520*2 = 41,600 B
    const int b  = blockIdx.x >> 6;
    const int s0 = (blockIdx.x & 63) * CM;
    const int tid = threadIdx.x;

    // stage window rows s0-4 .. s0+35 (embed gather, fp32 -> bf16)
    for (int i = tid; i < CW * (D_MODEL / 4); i += 512) {
        int row = i >> 7;                              // / (D_MODEL/4)
        int c4  = i & 127;
        int gs = s0 + row - PADW;
        float4 v = make_float4(0.f, 0.f, 0.f, 0.f);
        if (gs >= 0 && gs < S) {
            int tok = text[b * S + gs];
            v = ((const float4*)(emb + (size_t)tok * D_MODEL))[c4];
        }
        ushort4 o;
        o.x = f2bf(v.x); o.y = f2bf(v.y); o.z = f2bf(v.z); o.w = f2bf(v.w);
        *(ushort4*)(xs + row * LRS + c4 * 4) = o;
    }
    __syncthreads();

    const int wv   = tid >> 6;                         // 0..7
    const int lane = tid & 63;
    const int cl   = lane & 15;
    const int quad = lane >> 4;
    const int n0   = wv * 32;                          // wave's k-channel base

    f32x4 acc[2][2] = {};                              // [Msub][Nsub]

    for (int t = 0; t < KSZ; t++) {
        const unsigned short* wp =
            wtb + ((size_t)t * NK + n0 + cl) * D_MODEL + quad * 8;
        const unsigned short* ap = xs + (cl + t) * LRS + quad * 8;
        #pragma unroll 4
        for (int dc = 0; dc < D_MODEL / 32; dc++) {
            bf16x8 bfr0 = *(const bf16x8*)(wp + dc * 32);
            bf16x8 bfr1 = *(const bf16x8*)(wp + 16 * D_MODEL + dc * 32);
            bf16x8 afr[2];
            #pragma unroll
            for (int ms = 0; ms < 2; ms++)
                afr[ms] = *(const bf16x8*)(ap + ms * 16 * LRS + dc * 32);
            #pragma unroll
            for (int ms = 0; ms < 2; ms++) {
                acc[ms][0] = __builtin_amdgcn_mfma_f32_16x16x32_bf16(afr[ms], bfr0, acc[ms][0], 0, 0, 0);
                acc[ms][1] = __builtin_amdgcn_mfma_f32_16x16x32_bf16(afr[ms], bfr1, acc[ms][1], 0, 0, 0);
            }
        }
    }

    #pragma unroll
    for (int ns = 0; ns < 2; ns++) {
        const int k = n0 + ns * 16 + cl;
        const float bk = bias[k];
        #pragma unroll
        for (int ms = 0; ms < 2; ms++) {
            #pragma unroll
            for (int r = 0; r < 4; r++) {
                int s = s0 + ms * 16 + quad * 4 + r;
                float v = acc[ms][ns][r] + bk;
                float e = __expf(2.f * v);
                float th = 1.f - 2.f / (e + 1.f);      // tanh(v)
                xf[((size_t)b * S + s) * NK + k] = f2bf(th);
            }
        }
    }
}

// -------- MFMA flash attention with LDS double-buffered x tiles ------------
// Per block: 64 classes (4 waves x 16), 512 s-rows in 16 tiles of 32.
// Tile staged via global_load_lds (16B) with XOR swizzle: physical chunk
// p = j ^ (r&7) within each 512B row -> ds_read_b128 A-frags are 2-way
// bank-aliased (free).
__global__ __launch_bounds__(256) void attn_mfma(
    const unsigned short* __restrict__ xf, const unsigned short* __restrict__ Ub,
    const unsigned short* __restrict__ Fb, float* __restrict__ pm,
    float* __restrict__ pl, float* __restrict__ pg)
{
    __shared__ unsigned short xs[2 * 32 * NK];         // 2 x 16 KB
    const int b    = blockIdx.z;
    const int sp   = blockIdx.y;
    const int tid  = threadIdx.x;
    const int wv   = tid >> 6;
    const int lane = tid & 63;
    const int cl   = lane & 15;
    const int quad = lane >> 4;
    const int c0   = blockIdx.x * 64 + wv * 16;
    const int wvu  = __builtin_amdgcn_readfirstlane(wv);

    // Resident B-fragments for U and F (16 classes x 256 k): 64 VGPRs.
    bf16x8 uf[8], ff[8];
    const unsigned short* up = Ub + (size_t)(c0 + cl) * NK + quad * 8;
    const unsigned short* fp = Fb + (size_t)(c0 + cl) * NK + quad * 8;
    #pragma unroll
    for (int kk = 0; kk < 8; kk++) {
        uf[kk] = *(const bf16x8*)(up + kk * 32);
        ff[kk] = *(const bf16x8*)(fp + kk * 32);
    }

    const int sbeg = sp * (S / SSPLIT);
    const unsigned short* xb = xf + ((size_t)b * S + sbeg) * NK;

    // stage tile t into buffer bb: 1024 16B chunks, 4 per thread
    #define STAGE(bb, t)                                                      \
        {                                                                     \
            _Pragma("unroll")                                                 \
            for (int j = 0; j < 4; j++) {                                     \
                int C = j * 256 + tid;                                        \
                int r = C >> 5, p = C & 31;                                   \
                int jl = p ^ (r & 7);                                         \
                const unsigned short* src = xb + (size_t)((t) * 32 + r) * NK + jl * 8; \
                unsigned short* dst = (unsigned short*)xs + (bb) * 8192 + j * 2048 + wvu * 512; \
                GLOAD_LDS16(src, dst);                                        \
            }                                                                 \
        }

    STAGE(0, 0)

    float m = -1e30f, l = 0.f, G = 0.f;
    const int swz = cl & 7;                            // row&7 for both subtiles

    for (int t = 0; t < NTILES; t++) {
        __syncthreads();                               // tile t staged; buf free
        if (t + 1 < NTILES) STAGE((t + 1) & 1, t + 1)

        const unsigned short* bs = xs + (t & 1) * 8192;
        f32x4 sa0 = {0.f,0.f,0.f,0.f}, ga0 = {0.f,0.f,0.f,0.f};
        f32x4 sa1 = {0.f,0.f,0.f,0.f}, ga1 = {0.f,0.f,0.f,0.f};
        #pragma unroll
        for (int kk = 0; kk < 8; kk++) {
            int p0 = (quad + 4 * kk) ^ swz;            // physical chunk
            bf16x8 a0 = *(const bf16x8*)(bs + cl * NK + p0 * 8);
            bf16x8 a1 = *(const bf16x8*)(bs + (16 + cl) * NK + p0 * 8);
            sa0 = __builtin_amdgcn_mfma_f32_16x16x32_bf16(a0, uf[kk], sa0, 0, 0, 0);
            ga0 = __builtin_amdgcn_mfma_f32_16x16x32_bf16(a0, ff[kk], ga0, 0, 0, 0);
            sa1 = __builtin_amdgcn_mfma_f32_16x16x32_bf16(a1, uf[kk], sa1, 0, 0, 0);
            ga1 = __builtin_amdgcn_mfma_f32_16x16x32_bf16(a1, ff[kk], ga1, 0, 0, 0);
        }

        // online softmax over the tile's 32 s-rows (8 score values per lane)
        float tm = fmaxf(fmaxf(fmaxf(sa0[0], sa0[1]), fmaxf(sa0[2], sa0[3])),
                         fmaxf(fmaxf(sa1[0], sa1[1]), fmaxf(sa1[2], sa1[3])));
        tm = fmaxf(tm, __shfl_xor(tm, 16));
        tm = fmaxf(tm, __shfl_xor(tm, 32));
        float mn = fmaxf(m, tm);
        float sc = __expf(m - mn);
        l *= sc; G *= sc; m = mn;
        #pragma unroll
        for (int r = 0; r < 4; r++) {
            float e0 = __expf(sa0[r] - m);
            float e1 = __expf(sa1[r] - m);
            l += e0 + e1;
            G += e0 * ga0[r] + e1 * ga1[r];
        }
    }

    // reduce partial l/G across the 4 quads (m already quad-uniform)
    l += __shfl_xor(l, 16); l += __shfl_xor(l, 32);
    G += __shfl_xor(G, 16); G += __shfl_xor(G, 32);
    if (lane < 16) {
        size_t idx = ((size_t)b * SSPLIT + sp) * NC + c0 + lane;
        pm[idx] = m; pl[idx] = l; pg[idx] = G;
    }
}

// -------- combine S-split partials + bias -> y [b][c] ----------------------
__global__ __launch_bounds__(256) void combine_kernel(
    const float* __restrict__ pm, const float* __restrict__ pl,
    const float* __restrict__ pg, const float* __restrict__ fb,
    float* __restrict__ out)
{
    int idx = blockIdx.x * 256 + threadIdx.x;          // over B*NC
    if (idx >= B * NC) return;
    int b = idx / NC, c = idx % NC;
    float mm = -1e30f;
    #pragma unroll
    for (int sp = 0; sp < SSPLIT; sp++)
        mm = fmaxf(mm, pm[((size_t)b * SSPLIT + sp) * NC + c]);
    float l = 0.f, g = 0.f;
    #pragma unroll
    for (int sp = 0; sp < SSPLIT; sp++) {
        size_t i = ((size_t)b * SSPLIT + sp) * NC + c;
        float e = __expf(pm[i] - mm);
        l += pl[i] * e;
        g += pg[i] * e;
    }
    out[idx] = g / l + fb[c];
}

extern "C" void kernel_launch(void* const* d_in, const int* in_sizes, int n_in,
                              void* d_out, int out_size, void* d_ws, size_t ws_size,
                              hipStream_t stream) {
    const int*   text   = (const int*)  d_in[0];
    const float* emb    = (const float*)d_in[1];
    const float* conv_w = (const float*)d_in[2];
    const float* conv_b = (const float*)d_in[3];
    const float* U_w    = (const float*)d_in[4];
    const float* F_w    = (const float*)d_in[5];
    const float* f_b    = (const float*)d_in[6];
    float* out = (float*)d_out;

    char* ws = (char*)d_ws;
    unsigned short* xf  = (unsigned short*)ws; ws += (size_t)B * S * NK * 2;
    unsigned short* wtb = (unsigned short*)ws; ws += (size_t)KSZ * NK * D_MODEL * 2;
    unsigned short* Ub  = (unsigned short*)ws; ws += (size_t)NC * NK * 2;
    unsigned short* Fb  = (unsigned short*)ws; ws += (size_t)NC * NK * 2;
    float* pm = (float*)ws; ws += (size_t)SSPLIT * B * NC * 4;
    float* pl = (float*)ws; ws += (size_t)SSPLIT * B * NC * 4;
    float* pg = (float*)ws; ws += (size_t)SSPLIT * B * NC * 4;

    const int prep_n = PREP_W + 2 * PREP_UF;
    prep_all<<<dim3((prep_n + 255) / 256), 256, 0, stream>>>(conv_w, wtb, U_w, Ub, F_w, Fb);
    conv_mfma<<<dim3(B * S / CM), 512, 0, stream>>>(text, emb, wtb, conv_b, xf);
    attn_mfma<<<dim3(NC / 64, SSPLIT, B), 256, 0, stream>>>(xf, Ub, Fb, pm, pl, pg);
    combine_kernel<<<dim3((B * NC + 255) / 256), 256, 0, stream>>>(pm, pl, pg, f_b, out);
}

// Round 5
// 261.128 us; speedup vs baseline: 9.3819x; 1.2015x over previous
//
#include <hip/hip_runtime.h>
#include <math.h>

#define B 8
#define S 2048
#define D_MODEL 512
#define NK 256      // n_kernels (conv out channels / attention feature dim)
#define KSZ 9
#define NC 4096     // n_classes
#define PADW 4
#define SSPLIT 4    // attention s-dimension split
#define CM 64       // conv s-rows per block
#define CW (CM + 8) // staged window rows (72)
#define LRS 520     // conv LDS window row stride (bf16)
#define DCH 32      // conv weight-stage d-chunk
#define NSTG (KSZ * (D_MODEL / DCH))   // 144 weight stages
#define NTILES ((S / SSPLIT) / 32)     // 16 x-tiles per attn block

typedef __attribute__((ext_vector_type(8))) short bf16x8;
typedef __attribute__((ext_vector_type(4))) float f32x4;

static __device__ __forceinline__ unsigned short f2bf(float f) {
    unsigned int u = __float_as_uint(f);
    unsigned int r = (u + 0x7fffu + ((u >> 16) & 1u)) >> 16;
    return (unsigned short)r;
}

#define GLOAD_LDS16(g, l) __builtin_amdgcn_global_load_lds( \
    (const __attribute__((address_space(1))) void*)(g),     \
    (__attribute__((address_space(3))) void*)(l), 16, 0, 0)

// ---- fused prep: conv_w [k][d][t] -> wtb [t][k][d] bf16; U/F fp32 -> bf16 -
#define PREP_W (KSZ * NK * D_MODEL)
#define PREP_UF (NC * NK)
__global__ __launch_bounds__(256) void prep_all(
    const float* __restrict__ w, unsigned short* __restrict__ wtb,
    const float* __restrict__ U, unsigned short* __restrict__ Ub,
    const float* __restrict__ F, unsigned short* __restrict__ Fb)
{
    int idx = blockIdx.x * 256 + threadIdx.x;
    if (idx < PREP_W) {
        int d = idx % D_MODEL;
        int k = (idx / D_MODEL) % NK;
        int t = idx / (D_MODEL * NK);
        wtb[idx] = f2bf(w[((size_t)k * D_MODEL + d) * KSZ + t]);
        return;
    }
    idx -= PREP_W;
    if (idx < PREP_UF) { Ub[idx] = f2bf(U[idx]); return; }
    idx -= PREP_UF;
    if (idx < PREP_UF) { Fb[idx] = f2bf(F[idx]); }
}

// ---- embed-gather + MFMA conv1d (async-staged weights) + tanh -------------
// K-loop: 144 stages of (tap t, 32-d chunk h). Weight tile (256k x 32d,
// 16 KB) double-buffered in LDS via global_load_lds w=16. Swizzle: phys
// chunk jp holds logical j = jp ^ ((k>>1)&3)  -> B-frag ds_read_b128 is
// 2-way bank-aliased (free). Window (72 rows x 512d) staged once.
__global__ __launch_bounds__(512, 2) void conv_mfma(
    const int* __restrict__ text, const float* __restrict__ emb,
    const unsigned short* __restrict__ wtb, const float* __restrict__ bias,
    unsigned short* __restrict__ xf)
{
    __shared__ unsigned short xs[CW * LRS];        // 74,880 B
    __shared__ unsigned short wls[2 * NK * DCH];   // 32,768 B
    const int b  = blockIdx.x >> 5;                // S/CM = 32 s-blocks
    const int s0 = (blockIdx.x & 31) * CM;
    const int tid = threadIdx.x;

    // stage window rows s0-4 .. s0+67 (embed gather, fp32 -> bf16)
    for (int i = tid; i < CW * (D_MODEL / 4); i += 512) {   // 18 iters
        int row = i >> 7;                          // / (D_MODEL/4)
        int c4  = i & 127;
        int gs = s0 + row - PADW;
        float4 v = make_float4(0.f, 0.f, 0.f, 0.f);
        if (gs >= 0 && gs < S) {
            int tok = text[b * S + gs];
            v = ((const float4*)(emb + (size_t)tok * D_MODEL))[c4];
        }
        ushort4 o;
        o.x = f2bf(v.x); o.y = f2bf(v.y); o.z = f2bf(v.z); o.w = f2bf(v.w);
        *(ushort4*)(xs + row * LRS + c4 * 4) = o;
    }

    // stage weight tile stg into buffer bb: 1024 16B chunks, 2 per thread
    #define WSTAGE(bb, stg)                                                   \
        {                                                                     \
            int t_ = (stg) >> 4, h_ = (stg) & 15;                             \
            _Pragma("unroll")                                                 \
            for (int j = 0; j < 2; j++) {                                     \
                int C = j * 512 + tid;                                        \
                int k_ = C >> 2;                                              \
                int jl = (C & 3) ^ ((C >> 3) & 3);                            \
                const unsigned short* src =                                   \
                    wtb + ((size_t)(t_ * NK + k_)) * D_MODEL + h_ * DCH + jl * 8; \
                unsigned short* dst = wls + (bb) * (NK * DCH) + C * 8;        \
                GLOAD_LDS16(src, dst);                                        \
            }                                                                 \
        }

    WSTAGE(0, 0)

    const int wv   = tid >> 6;                     // 0..7
    const int lane = tid & 63;
    const int cl   = lane & 15;
    const int quad = lane >> 4;
    const int n0   = wv * 32;                      // wave's k-channel base
    const int jp   = quad ^ ((cl >> 1) & 3);       // phys weight chunk

    f32x4 acc[4][2] = {};                          // [Msub][Nsub]

    for (int stg = 0; stg < NSTG; stg++) {
        __syncthreads();                           // stage stg (and window) ready
        if (stg + 1 < NSTG) WSTAGE((stg + 1) & 1, stg + 1)

        const int t = stg >> 4, h = stg & 15;
        const unsigned short* wb = wls + (stg & 1) * (NK * DCH);
        const unsigned short* ap = xs + (cl + t) * LRS + h * DCH + quad * 8;

        bf16x8 b0 = *(const bf16x8*)(wb + (n0 + cl) * DCH + jp * 8);
        bf16x8 b1 = *(const bf16x8*)(wb + (n0 + 16 + cl) * DCH + jp * 8);
        #pragma unroll
        for (int ms = 0; ms < 4; ms++) {
            bf16x8 a = *(const bf16x8*)(ap + ms * 16 * LRS);
            acc[ms][0] = __builtin_amdgcn_mfma_f32_16x16x32_bf16(a, b0, acc[ms][0], 0, 0, 0);
            acc[ms][1] = __builtin_amdgcn_mfma_f32_16x16x32_bf16(a, b1, acc[ms][1], 0, 0, 0);
        }
    }

    // epilogue: bias + tanh -> bf16. C-layout: s=ms*16+quad*4+r, k=ns*16+cl
    #pragma unroll
    for (int ns = 0; ns < 2; ns++) {
        const int k = n0 + ns * 16 + cl;
        const float bk = bias[k];
        #pragma unroll
        for (int ms = 0; ms < 4; ms++) {
            #pragma unroll
            for (int r = 0; r < 4; r++) {
                int s = s0 + ms * 16 + quad * 4 + r;
                float v = acc[ms][ns][r] + bk;
                float e = __expf(2.f * v);
                float th = 1.f - 2.f / (e + 1.f);  // tanh(v)
                xf[((size_t)b * S + s) * NK + k] = f2bf(th);
            }
        }
    }
}

// -------- MFMA flash attention: 32 classes/wave, LDS double-buffered x -----
// A-frags (x rows) reused across 2 class-groups: 64 MFMA per 16 ds_read_b128.
__global__ __launch_bounds__(256, 2) void attn_mfma(
    const unsigned short* __restrict__ xf, const unsigned short* __restrict__ Ub,
    const unsigned short* __restrict__ Fb, float* __restrict__ pm,
    float* __restrict__ pl, float* __restrict__ pg)
{
    __shared__ unsigned short xsa[2 * 32 * NK];    // 2 x 16 KB
    const int b    = blockIdx.z;
    const int sp   = blockIdx.y;
    const int tid  = threadIdx.x;
    const int wv   = tid >> 6;
    const int lane = tid & 63;
    const int cl   = lane & 15;
    const int quad = lane >> 4;
    const int c0   = blockIdx.x * 128 + wv * 32;
    const int wvu  = __builtin_amdgcn_readfirstlane(wv);

    // Resident B-fragments: 2 class-groups x (U,F) x 256 k = 128 VGPRs.
    bf16x8 uf[2][8], ff[2][8];
    #pragma unroll
    for (int cg = 0; cg < 2; cg++) {
        const unsigned short* up = Ub + (size_t)(c0 + cg * 16 + cl) * NK + quad * 8;
        const unsigned short* fp = Fb + (size_t)(c0 + cg * 16 + cl) * NK + quad * 8;
        #pragma unroll
        for (int kk = 0; kk < 8; kk++) {
            uf[cg][kk] = *(const bf16x8*)(up + kk * 32);
            ff[cg][kk] = *(const bf16x8*)(fp + kk * 32);
        }
    }

    const int sbeg = sp * (S / SSPLIT);
    const unsigned short* xb = xf + ((size_t)b * S + sbeg) * NK;

    // stage x tile t: 1024 16B chunks, 4/thread; XOR swizzle p = j ^ (r&7)
    #define STAGE(bb, t)                                                      \
        {                                                                     \
            _Pragma("unroll")                                                 \
            for (int j = 0; j < 4; j++) {                                     \
                int C = j * 256 + tid;                                        \
                int r = C >> 5, p = C & 31;                                   \
                int jl = p ^ (r & 7);                                         \
                const unsigned short* src = xb + (size_t)((t) * 32 + r) * NK + jl * 8; \
                unsigned short* dst = xsa + (bb) * 8192 + j * 2048 + wvu * 512; \
                GLOAD_LDS16(src, dst);                                        \
            }                                                                 \
        }

    STAGE(0, 0)

    float m[2] = {-1e30f, -1e30f}, l[2] = {0.f, 0.f}, G[2] = {0.f, 0.f};
    const int swz = cl & 7;

    for (int t = 0; t < NTILES; t++) {
        __syncthreads();
        if (t + 1 < NTILES) STAGE((t + 1) & 1, t + 1)

        const unsigned short* bs = xsa + (t & 1) * 8192;
        f32x4 sa[2][2] = {}, ga[2][2] = {};        // [rowgrp][cg]
        #pragma unroll
        for (int kk = 0; kk < 8; kk++) {
            int p0 = (quad + 4 * kk) ^ swz;
            bf16x8 a0 = *(const bf16x8*)(bs + cl * NK + p0 * 8);
            bf16x8 a1 = *(const bf16x8*)(bs + (16 + cl) * NK + p0 * 8);
            #pragma unroll
            for (int cg = 0; cg < 2; cg++) {
                sa[0][cg] = __builtin_amdgcn_mfma_f32_16x16x32_bf16(a0, uf[cg][kk], sa[0][cg], 0, 0, 0);
                ga[0][cg] = __builtin_amdgcn_mfma_f32_16x16x32_bf16(a0, ff[cg][kk], ga[0][cg], 0, 0, 0);
                sa[1][cg] = __builtin_amdgcn_mfma_f32_16x16x32_bf16(a1, uf[cg][kk], sa[1][cg], 0, 0, 0);
                ga[1][cg] = __builtin_amdgcn_mfma_f32_16x16x32_bf16(a1, ff[cg][kk], ga[1][cg], 0, 0, 0);
            }
        }

        #pragma unroll
        for (int cg = 0; cg < 2; cg++) {
            float tm = fmaxf(fmaxf(fmaxf(sa[0][cg][0], sa[0][cg][1]), fmaxf(sa[0][cg][2], sa[0][cg][3])),
                             fmaxf(fmaxf(sa[1][cg][0], sa[1][cg][1]), fmaxf(sa[1][cg][2], sa[1][cg][3])));
            tm = fmaxf(tm, __shfl_xor(tm, 16));
            tm = fmaxf(tm, __shfl_xor(tm, 32));
            float mn = fmaxf(m[cg], tm);
            float sc = __expf(m[cg] - mn);
            l[cg] *= sc; G[cg] *= sc; m[cg] = mn;
            #pragma unroll
            for (int r = 0; r < 4; r++) {
                float e0 = __expf(sa[0][cg][r] - mn);
                float e1 = __expf(sa[1][cg][r] - mn);
                l[cg] += e0 + e1;
                G[cg] += e0 * ga[0][cg][r] + e1 * ga[1][cg][r];
            }
        }
    }

    #pragma unroll
    for (int cg = 0; cg < 2; cg++) {
        l[cg] += __shfl_xor(l[cg], 16); l[cg] += __shfl_xor(l[cg], 32);
        G[cg] += __shfl_xor(G[cg], 16); G[cg] += __shfl_xor(G[cg], 32);
    }
    if (lane < 16) {
        #pragma unroll
        for (int cg = 0; cg < 2; cg++) {
            size_t idx = ((size_t)b * SSPLIT + sp) * NC + c0 + cg * 16 + lane;
            pm[idx] = m[cg]; pl[idx] = l[cg]; pg[idx] = G[cg];
        }
    }
}

// -------- combine S-split partials + bias -> y [b][c] ----------------------
__global__ __launch_bounds__(256) void combine_kernel(
    const float* __restrict__ pm, const float* __restrict__ pl,
    const float* __restrict__ pg, const float* __restrict__ fb,
    float* __restrict__ out)
{
    int idx = blockIdx.x * 256 + threadIdx.x;      // over B*NC
    if (idx >= B * NC) return;
    int b = idx / NC, c = idx % NC;
    float mm = -1e30f;
    #pragma unroll
    for (int sp = 0; sp < SSPLIT; sp++)
        mm = fmaxf(mm, pm[((size_t)b * SSPLIT + sp) * NC + c]);
    float l = 0.f, g = 0.f;
    #pragma unroll
    for (int sp = 0; sp < SSPLIT; sp++) {
        size_t i = ((size_t)b * SSPLIT + sp) * NC + c;
        float e = __expf(pm[i] - mm);
        l += pl[i] * e;
        g += pg[i] * e;
    }
    out[idx] = g / l + fb[c];
}

extern "C" void kernel_launch(void* const* d_in, const int* in_sizes, int n_in,
                              void* d_out, int out_size, void* d_ws, size_t ws_size,
                              hipStream_t stream) {
    const int*   text   = (const int*)  d_in[0];
    const float* emb    = (const float*)d_in[1];
    const float* conv_w = (const float*)d_in[2];
    const float* conv_b = (const float*)d_in[3];
    const float* U_w    = (const float*)d_in[4];
    const float* F_w    = (const float*)d_in[5];
    const float* f_b    = (const float*)d_in[6];
    float* out = (float*)d_out;

    char* ws = (char*)d_ws;
    unsigned short* xf  = (unsigned short*)ws; ws += (size_t)B * S * NK * 2;
    unsigned short* wtb = (unsigned short*)ws; ws += (size_t)KSZ * NK * D_MODEL * 2;
    unsigned short* Ub  = (unsigned short*)ws; ws += (size_t)NC * NK * 2;
    unsigned short* Fb  = (unsigned short*)ws; ws += (size_t)NC * NK * 2;
    float* pm = (float*)ws; ws += (size_t)SSPLIT * B * NC * 4;
    float* pl = (float*)ws; ws += (size_t)SSPLIT * B * NC * 4;
    float* pg = (float*)ws; ws += (size_t)SSPLIT * B * NC * 4;

    const int prep_n = PREP_W + 2 * PREP_UF;
    prep_all<<<dim3((prep_n + 255) / 256), 256, 0, stream>>>(conv_w, wtb, U_w, Ub, F_w, Fb);
    conv_mfma<<<dim3(B * S / CM), 512, 0, stream>>>(text, emb, wtb, conv_b, xf);
    attn_mfma<<<dim3(NC / 128, SSPLIT, B), 256, 0, stream>>>(xf, Ub, Fb, pm, pl, pg);
    combine_kernel<<<dim3((B * NC + 255) / 256), 256, 0, stream>>>(pm, pl, pg, f_b, out);
}